// Round 3
// baseline (868.684 us; speedup 1.0000x reference)
//
#include <hip/hip_runtime.h>
#include <math.h>

#define NTOK   16384
#define DIM    4096
#define NEXP   256
#define NGRP   8
#define TOPKG  4
#define TOPK   8

// ---------------- GEMM: logits[T,E] = X[T,D] * W[E,D]^T (fp32) ----------------
// 64x32 block tile, ONE wave per block (64 threads), 8x4 micro-tile per thread.
// 2048 blocks -> 8 blocks/CU -> 2 waves/SIMD (grid-limited). Sequential-K
// accumulation: logits bitwise identical to rounds 1-2 (keeps top-k ties frozen).
#define BM 64
#define BN 32
#define BK 16
#define LDA (BM + 4)   // 68
#define LDB (BN + 4)   // 36

__global__ __launch_bounds__(64, 4) void gate_gemm(const float* __restrict__ X,
                                                   const float* __restrict__ W,
                                                   float* __restrict__ L) {
    __shared__ float As[BK][LDA];   // 4.35 KB
    __shared__ float Bs[BK][LDB];   // 2.30 KB

    const int t  = threadIdx.x;            // 0..63
    const int bm = blockIdx.y * BM;        // token block
    const int bn = blockIdx.x * BN;        // expert block

    // staging: A: thread t owns row t, 4 float4 (k-quads 0..3)
    //          B: thread t owns row t>>1, 2 float4 (k-quads bq..bq+1)
    const int brow = t >> 1;
    const int bq   = (t & 1) * 2;
    const float* xa = X + (size_t)(bm + t) * DIM;
    const float* wb = W + (size_t)(bn + brow) * DIM + bq * 4;

    // compute: thread owns rows ty*8..+7, cols tx*4..+3
    const int tx = t & 7;
    const int ty = t >> 3;

    float4 pa[4], pb[2];
#pragma unroll
    for (int q = 0; q < 4; ++q) pa[q] = *(const float4*)(xa + q * 4);
#pragma unroll
    for (int i = 0; i < 2; ++i) pb[i] = *(const float4*)(wb + i * 4);

    float acc[8][4] = {};

    for (int k0 = 0; k0 < DIM; k0 += BK) {
        __syncthreads();   // previous iter's fragment reads done (1-wave: cheap)
#pragma unroll
        for (int q = 0; q < 4; ++q)
#pragma unroll
            for (int j = 0; j < 4; ++j)
                As[q * 4 + j][t] = (&pa[q].x)[j];
#pragma unroll
        for (int i = 0; i < 2; ++i)
#pragma unroll
            for (int j = 0; j < 4; ++j)
                Bs[(bq + i) * 4 + j][brow] = (&pb[i].x)[j];
        __syncthreads();

        if (k0 + BK < DIM) {   // register prefetch of next tile overlaps compute
#pragma unroll
            for (int q = 0; q < 4; ++q) pa[q] = *(const float4*)(xa + k0 + BK + q * 4);
#pragma unroll
            for (int i = 0; i < 2; ++i) pb[i] = *(const float4*)(wb + k0 + BK + i * 4);
        }

#pragma unroll
        for (int k = 0; k < BK; ++k) {
            float4 a0 = *(const float4*)&As[k][ty * 8];
            float4 a1 = *(const float4*)&As[k][ty * 8 + 4];
            float4 b  = *(const float4*)&Bs[k][tx * 4];
            const float ar[8] = {a0.x, a0.y, a0.z, a0.w, a1.x, a1.y, a1.z, a1.w};
            const float br[4] = {b.x, b.y, b.z, b.w};
#pragma unroll
            for (int i = 0; i < 8; ++i)
#pragma unroll
                for (int j = 0; j < 4; ++j)
                    acc[i][j] = fmaf(ar[i], br[j], acc[i][j]);
        }
    }

#pragma unroll
    for (int i = 0; i < 8; ++i) {
        *(float4*)&L[(size_t)(bm + ty * 8 + i) * NEXP + bn + tx * 4] =
            make_float4(acc[i][0], acc[i][1], acc[i][2], acc[i][3]);
    }
}

// ---------------- Routing: one wave (64 lanes) per token ----------------
// lane holds experts 4*lane .. 4*lane+3; group = lane>>3 (8 lanes/group of 32)
__global__ __launch_bounds__(256) void gate_route(const float* __restrict__ L,
                                                  float* __restrict__ outw,
                                                  float* __restrict__ outi) {
    const int lane = threadIdx.x & 63;
    const int tok  = (blockIdx.x * blockDim.x + threadIdx.x) >> 6;
    if (tok >= NTOK) return;

    const float* row = L + (size_t)tok * NEXP;
    float4 v = *(const float4*)(row + lane * 4);
    float l[4] = {v.x, v.y, v.z, v.w};

    // wave-wide max logit
    float lmax = fmaxf(fmaxf(l[0], l[1]), fmaxf(l[2], l[3]));
    float m = lmax;
#pragma unroll
    for (int o = 32; o; o >>= 1) m = fmaxf(m, __shfl_xor(m, o));

    // softmax denominator over ALL 256 experts
    float s = __expf(l[0] - m) + __expf(l[1] - m) + __expf(l[2] - m) + __expf(l[3] - m);
#pragma unroll
    for (int o = 32; o; o >>= 1) s += __shfl_xor(s, o);

    // per-group max logit (monotone proxy for max softmax score)
    float gm = lmax;
#pragma unroll
    for (int o = 4; o; o >>= 1) gm = fmaxf(gm, __shfl_xor(gm, o));

    // rank my group among the 8 group maxes (ties -> lower group index wins)
    const int g = lane >> 3;
    int rank = 0;
#pragma unroll
    for (int gg = 0; gg < 8; ++gg) {
        float vg = __shfl(gm, gg * 8);
        rank += (vg > gm) || (vg == gm && gg < g);
    }
    const bool allowed = rank < TOPKG;

    float mv[4];
#pragma unroll
    for (int j = 0; j < 4; ++j) mv[j] = allowed ? l[j] : -INFINITY;

    float wsel = 0.0f;
    int   isel = 0;

    for (int k = 0; k < TOPK; ++k) {
        // local argmax among this lane's 4 (tie -> lower index via strict >)
        float bv = mv[0];
        int   bi = lane * 4;
        if (mv[1] > bv) { bv = mv[1]; bi = lane * 4 + 1; }
        if (mv[2] > bv) { bv = mv[2]; bi = lane * 4 + 2; }
        if (mv[3] > bv) { bv = mv[3]; bi = lane * 4 + 3; }
        // wave argmax with (value desc, index asc) lexicographic order
#pragma unroll
        for (int o = 32; o; o >>= 1) {
            float ov = __shfl_xor(bv, o);
            int   oi = __shfl_xor(bi, o);
            if (ov > bv || (ov == bv && oi < bi)) { bv = ov; bi = oi; }
        }
        if (lane == k) { wsel = __expf(bv - m) / s; isel = bi; }
        if ((bi >> 2) == lane) mv[bi & 3] = -INFINITY;  // remove selected
    }

    if (lane < TOPK) {
        outw[(size_t)tok * TOPK + lane] = wsel;
        outi[(size_t)tok * TOPK + lane] = (float)isel;
    }
}

extern "C" void kernel_launch(void* const* d_in, const int* in_sizes, int n_in,
                              void* d_out, int out_size, void* d_ws, size_t ws_size,
                              hipStream_t stream) {
    const float* x = (const float*)d_in[0];   // [16384, 4096]
    const float* w = (const float*)d_in[1];   // [256, 4096]
    float* logits  = (float*)d_ws;            // [16384, 256] = 16 MB
    float* outw    = (float*)d_out;                       // [16384, 8] weights
    float* outi    = (float*)d_out + (size_t)NTOK * TOPK; // [16384, 8] idx (as float)

    dim3 ggrid(NEXP / BN, NTOK / BM);   // (8, 256) = 2048 blocks, 8/CU
    gate_gemm<<<ggrid, 64, 0, stream>>>(x, w, logits);

    int rblocks = (NTOK * 64) / 256;    // 4096 blocks
    gate_route<<<rblocks, 256, 0, stream>>>(logits, outw, outi);
}

// Round 4
// 433.472 us; speedup vs baseline: 2.0040x; 2.0040x over previous
//
#include <hip/hip_runtime.h>
#include <math.h>
#include <stdint.h>

#define NTOK   16384
#define DIM    4096
#define NEXP   256
#define TOPKG  4
#define TOPK   8
#define NSPLIT 4
#define KCHUNK (DIM / NSPLIT)   // 1024
#define BM     128
#define BK     32

typedef float v4f   __attribute__((ext_vector_type(4)));
typedef short short8 __attribute__((ext_vector_type(8)));

__device__ inline unsigned short f2bf(float x) {           // round-to-nearest-even
    unsigned u = __float_as_uint(x);
    return (unsigned short)((u + 0x7fffu + ((u >> 16) & 1u)) >> 16);
}
__device__ inline float bf2f(unsigned short h) {
    return __uint_as_float(((unsigned)h) << 16);
}

// ---- W fp32 -> bf16 (hi, lo) row-major [256][4096], done once per call ----
__global__ __launch_bounds__(256) void wprep(const float* __restrict__ W,
                                             unsigned short* __restrict__ Wh,
                                             unsigned short* __restrict__ Wl) {
    int i = (blockIdx.x * 256 + threadIdx.x) * 4;
    float4 v = *(const float4*)(W + i);
    ushort4 h, l;
    h.x = f2bf(v.x); l.x = f2bf(v.x - bf2f(h.x));
    h.y = f2bf(v.y); l.y = f2bf(v.y - bf2f(h.y));
    h.z = f2bf(v.z); l.z = f2bf(v.z - bf2f(h.z));
    h.w = f2bf(v.w); l.w = f2bf(v.w - bf2f(h.w));
    *(ushort4*)(Wh + i) = h;
    *(ushort4*)(Wl + i) = l;
}

// ---- GEMM: P[z][t][e] = sum_{k in chunk z} X[t,k] W[e,k], bf16x2 3-pass MFMA ----
// block: 256 thr (4 waves), tile 128 tokens x 256 experts, K-chunk 1024.
// wave w owns cols 64w..64w+63 (4 col-tiles), rows 0..127 (8 row-tiles).
__global__ __launch_bounds__(256, 2) void gate_gemm(const float* __restrict__ X,
                                                    const unsigned short* __restrict__ Wh,
                                                    const unsigned short* __restrict__ Wl,
                                                    float* __restrict__ P) {
    __shared__ __align__(16) unsigned short Ah[BM * BK];    // [128][32] bf16
    __shared__ __align__(16) unsigned short Al[BM * BK];
    __shared__ __align__(16) unsigned short Bh[NEXP * BK];  // [256][32] bf16
    __shared__ __align__(16) unsigned short Bl[NEXP * BK];

    const int t  = threadIdx.x;
    const int bm = blockIdx.x * BM;
    const int z  = blockIdx.y;
    const int k0 = z * KCHUNK;

    const int l  = t & 63;
    const int w  = t >> 6;
    const int lm = l & 15;     // m/n within 16x16 tile
    const int lq = l >> 4;     // k-quad (0..3)

    // A staging: thread t -> row t>>1, k-half (t&1)*16
    const int ar = t >> 1;
    const int ak = (t & 1) * 16;
    const float* xrow = X + (size_t)(bm + ar) * DIM + k0 + ak;

    v4f acc[8][4] = {};

    for (int kr = 0; kr < KCHUNK; kr += BK) {
        __syncthreads();   // prior round's frag reads done before overwrite

        // B: bf16 h/l direct global->LDS (W chunk is L2-resident)
#pragma unroll
        for (int i = 0; i < 4; ++i) {
            int flat = i * 256 + t;          // 0..1023
            int e = flat >> 2, q = flat & 3; // row, 16B-quarter
            const unsigned short* gh = Wh + (size_t)e * DIM + k0 + kr + q * 8;
            const unsigned short* gl = Wl + (size_t)e * DIM + k0 + kr + q * 8;
            __builtin_amdgcn_global_load_lds(
                (const __attribute__((address_space(1))) unsigned int*)gh,
                (__attribute__((address_space(3))) unsigned int*)&Bh[flat * 8], 16, 0, 0);
            __builtin_amdgcn_global_load_lds(
                (const __attribute__((address_space(1))) unsigned int*)gl,
                (__attribute__((address_space(3))) unsigned int*)&Bl[flat * 8], 16, 0, 0);
        }

        // A: fp32 load + split-convert + LDS write (16 elems/thread)
        float4 xv[4];
#pragma unroll
        for (int i = 0; i < 4; ++i) xv[i] = *(const float4*)(xrow + kr + i * 4);
#pragma unroll
        for (int i = 0; i < 4; ++i) {
            ushort4 h, lo;
            h.x = f2bf(xv[i].x); lo.x = f2bf(xv[i].x - bf2f(h.x));
            h.y = f2bf(xv[i].y); lo.y = f2bf(xv[i].y - bf2f(h.y));
            h.z = f2bf(xv[i].z); lo.z = f2bf(xv[i].z - bf2f(h.z));
            h.w = f2bf(xv[i].w); lo.w = f2bf(xv[i].w - bf2f(h.w));
            *(ushort4*)&Ah[ar * BK + ak + i * 4] = h;
            *(ushort4*)&Al[ar * BK + ak + i * 4] = lo;
        }

        __syncthreads();   // drains vmcnt(0): global_load_lds data visible

        short8 bh[4], bl[4];
#pragma unroll
        for (int c = 0; c < 4; ++c) {
            int e = w * 64 + c * 16 + lm;
            bh[c] = *(const short8*)&Bh[e * BK + lq * 8];
            bl[c] = *(const short8*)&Bl[e * BK + lq * 8];
        }
#pragma unroll
        for (int r = 0; r < 8; ++r) {
            int m = r * 16 + lm;
            short8 ah = *(const short8*)&Ah[m * BK + lq * 8];
            short8 al = *(const short8*)&Al[m * BK + lq * 8];
#pragma unroll
            for (int c = 0; c < 4; ++c) {
                acc[r][c] = __builtin_amdgcn_mfma_f32_16x16x32_bf16(ah, bh[c], acc[r][c], 0, 0, 0);
                acc[r][c] = __builtin_amdgcn_mfma_f32_16x16x32_bf16(ah, bl[c], acc[r][c], 0, 0, 0);
                acc[r][c] = __builtin_amdgcn_mfma_f32_16x16x32_bf16(al, bh[c], acc[r][c], 0, 0, 0);
            }
        }
    }

    // epilogue: C/D layout col=lane&15, row=lq*4+reg (verified m89/m91)
    float* Pb = P + ((size_t)z * NTOK + bm) * NEXP;
#pragma unroll
    for (int r = 0; r < 8; ++r)
#pragma unroll
        for (int c = 0; c < 4; ++c)
#pragma unroll
            for (int g = 0; g < 4; ++g)
                Pb[(size_t)(r * 16 + lq * 4 + g) * NEXP + w * 64 + c * 16 + lm] = acc[r][c][g];
}

// ---- fused reduce (4 partials, fixed order) + routing: one wave per token ----
__global__ __launch_bounds__(256) void gate_route(const float* __restrict__ P,
                                                  float* __restrict__ outw,
                                                  float* __restrict__ outi) {
    const int lane = threadIdx.x & 63;
    const int tok  = (blockIdx.x * blockDim.x + threadIdx.x) >> 6;
    if (tok >= NTOK) return;

    float l[4] = {0.f, 0.f, 0.f, 0.f};
#pragma unroll
    for (int z = 0; z < NSPLIT; ++z) {   // fixed order: deterministic across runs
        float4 v = *(const float4*)(P + ((size_t)z * NTOK + tok) * NEXP + lane * 4);
        l[0] += v.x; l[1] += v.y; l[2] += v.z; l[3] += v.w;
    }

    float lmax = fmaxf(fmaxf(l[0], l[1]), fmaxf(l[2], l[3]));
    float m = lmax;
#pragma unroll
    for (int o = 32; o; o >>= 1) m = fmaxf(m, __shfl_xor(m, o));

    float s = __expf(l[0] - m) + __expf(l[1] - m) + __expf(l[2] - m) + __expf(l[3] - m);
#pragma unroll
    for (int o = 32; o; o >>= 1) s += __shfl_xor(s, o);

    float gm = lmax;
#pragma unroll
    for (int o = 4; o; o >>= 1) gm = fmaxf(gm, __shfl_xor(gm, o));

    const int g = lane >> 3;
    int rank = 0;
#pragma unroll
    for (int gg = 0; gg < 8; ++gg) {
        float vg = __shfl(gm, gg * 8);
        rank += (vg > gm) || (vg == gm && gg < g);
    }
    const bool allowed = rank < TOPKG;

    float mv[4];
#pragma unroll
    for (int j = 0; j < 4; ++j) mv[j] = allowed ? l[j] : -INFINITY;

    float wsel = 0.0f;
    int   isel = 0;

    for (int k = 0; k < TOPK; ++k) {
        float bv = mv[0];
        int   bi = lane * 4;
        if (mv[1] > bv) { bv = mv[1]; bi = lane * 4 + 1; }
        if (mv[2] > bv) { bv = mv[2]; bi = lane * 4 + 2; }
        if (mv[3] > bv) { bv = mv[3]; bi = lane * 4 + 3; }
#pragma unroll
        for (int o = 32; o; o >>= 1) {
            float ov = __shfl_xor(bv, o);
            int   oi = __shfl_xor(bi, o);
            if (ov > bv || (ov == bv && oi < bi)) { bv = ov; bi = oi; }
        }
        if (lane == k) { wsel = __expf(bv - m) / s; isel = bi; }
        if ((bi >> 2) == lane) mv[bi & 3] = -INFINITY;
    }

    if (lane < TOPK) {
        outw[(size_t)tok * TOPK + lane] = wsel;
        outi[(size_t)tok * TOPK + lane] = (float)isel;
    }
}

extern "C" void kernel_launch(void* const* d_in, const int* in_sizes, int n_in,
                              void* d_out, int out_size, void* d_ws, size_t ws_size,
                              hipStream_t stream) {
    const float* x  = (const float*)d_in[0];   // [16384, 4096]
    const float* wt = (const float*)d_in[1];   // [256, 4096]

    // ws layout: partials [4][16384][256] f32 (64 MB) | Wh (2 MB) | Wl (2 MB)
    float* P = (float*)d_ws;
    unsigned short* Wh = (unsigned short*)((char*)d_ws + (size_t)NSPLIT * NTOK * NEXP * 4);
    unsigned short* Wl = Wh + (size_t)NEXP * DIM;

    float* outw = (float*)d_out;
    float* outi = (float*)d_out + (size_t)NTOK * TOPK;

    wprep<<<(NEXP * DIM) / (256 * 4), 256, 0, stream>>>(wt, Wh, Wl);

    dim3 ggrid(NTOK / BM, NSPLIT);   // (128, 4) = 512 blocks, 2/CU
    gate_gemm<<<ggrid, 256, 0, stream>>>(x, Wh, Wl, P);

    gate_route<<<(NTOK * 64) / 256, 256, 0, stream>>>(P, outw, outi);
}